// Round 13
// baseline (185.092 us; speedup 1.0000x reference)
//
#include <hip/hip_runtime.h>

#define BS 64
#define SEQ 2048
#define LQ 128
#define NH 128

typedef short bf16x8 __attribute__((ext_vector_type(8)));
typedef float f32x4 __attribute__((ext_vector_type(4)));
typedef unsigned short u16x4 __attribute__((ext_vector_type(4)));
typedef unsigned uint2v __attribute__((ext_vector_type(2)));

__device__ __forceinline__ unsigned short f2bf(float f) {
  unsigned u = __float_as_uint(f);
  u = (u + 0x7FFFu + ((u >> 16) & 1u)) >> 16;
  return (unsigned short)u;
}
__device__ __forceinline__ float b2f(unsigned short u) {
  return __uint_as_float((unsigned)u << 16);
}
__device__ __forceinline__ float sigm(float x) { return 1.f / (1.f + __expf(-x)); }
__device__ __forceinline__ float gelu_f(float x) { return 0.5f * x * (1.f + erff(x * 0.70710678118654752f)); }
__device__ __forceinline__ float fexp2(float x) { float y; asm("v_exp_f32 %0, %1" : "=v"(y) : "v"(x)); return y; }
__device__ __forceinline__ float frcp(float x) { float y; asm("v_rcp_f32 %0, %1" : "=v"(y) : "v"(x)); return y; }
__device__ __forceinline__ unsigned cvtpk(float lo, float hi) {
  unsigned d; asm("v_cvt_pk_bf16_f32 %0, %1, %2" : "=v"(d) : "v"(lo), "v"(hi)); return d;
}

// LDS-only barrier (no vmcnt drain at source level).
__device__ __forceinline__ void softbar() {
  asm volatile("s_waitcnt lgkmcnt(0)" ::: "memory");
  __builtin_amdgcn_s_barrier();
  __builtin_amdgcn_sched_barrier(0);
}

// ---------------- prep: q-proj (C2-scaled) + fold (9 blocks) ----------------
__global__ __launch_bounds__(384) void k_prep(
    const float* __restrict__ qw, const float* __restrict__ qb,
    const float* __restrict__ lw, const float* __restrict__ lb,
    const float* __restrict__ pw, const float* __restrict__ pb,
    const float* __restrict__ wih, const float* __restrict__ bih,
    const float* __restrict__ bhh,
    const float* __restrict__ aow, const float* __restrict__ aob,
    unsigned short* __restrict__ qbf, float* __restrict__ fwc) {
  const int tid = threadIdx.x;
  const int blk = blockIdx.x;
  if (blk < 8) {
    __shared__ float emb[16 * 132];
    __shared__ float Ac[128], Bc[128];
    const float C2 = 0.25505654f;  // log2(e)/sqrt(32), folded into q
    if (tid < 128) {
      Ac[tid] = (tid == 0) ? lw[0] : pw[tid - 1];
      Bc[tid] = (tid == 0) ? lb[0] : pb[tid - 1];
    }
    __syncthreads();
    if (tid < 256) {
      int lq = tid >> 4, e0 = (tid & 15) * 8;
      float tv = (float)(blk * 16 + lq) * (1.f / 127.f);
#pragma unroll
      for (int k = 0; k < 8; ++k) {
        int e = e0 + k;
        float arg = fmaf(tv, Ac[e], Bc[e]);
        emb[lq * 132 + e] = (e == 0) ? arg : __sinf(arg);
      }
    }
    __syncthreads();
    if (tid < 256) {
      const int c = tid & 127, lh = tid >> 7;
      float acc[8];
#pragma unroll
      for (int i = 0; i < 8; ++i) acc[i] = qb[c];
      for (int e4 = 0; e4 < 32; ++e4) {
        float4 wv = *(const float4*)(qw + c * 128 + e4 * 4);
#pragma unroll
        for (int i = 0; i < 8; ++i) {
          const float* er = &emb[(lh * 8 + i) * 132 + e4 * 4];
          acc[i] += wv.x * er[0] + wv.y * er[1] + wv.z * er[2] + wv.w * er[3];
        }
      }
#pragma unroll
      for (int i = 0; i < 8; ++i) {
        int lq = blk * 16 + lh * 8 + i;
        qbf[((c >> 5) * LQ + lq) * 32 + (c & 31)] = f2bf(acc[i] * C2);
      }
    }
  } else {
    const int g = tid;
    const float sc = (g < 256) ? -1.4426950408889634f : 2.8853900817779268f;
    float fw[8];
#pragma unroll
    for (int c = 0; c < 8; ++c) fw[c] = 0.f;
    float cg = bih[g] + (g < 256 ? bhh[g] : 0.f);
    for (int j = 0; j < 128; ++j) {
      float w = wih[g * 128 + j];
      cg = fmaf(w, aob[j], cg);
#pragma unroll
      for (int c = 0; c < 8; ++c) fw[c] = fmaf(w, aow[j * 8 + c], fw[c]);
    }
#pragma unroll
    for (int c = 0; c < 8; ++c) fwc[g * 12 + c] = fw[c] * sc;
    fwc[g * 12 + 8] = cg * sc;
  }
}

// ---------------- x-gates: xg[t][quad=96][b=64][4] bf16 (gru-coalesced) ----------------
__global__ __launch_bounds__(384) void k_xgate(
    const float* __restrict__ fwc, const float* __restrict__ part,
    unsigned short* __restrict__ xg) {
  __shared__ float at[64][8];
  const int tid = threadIdx.x;
  const int t = blockIdx.x;
  if (tid < 256) {
    int b = tid >> 2, h = tid & 3;
    const float* p = part + ((size_t)(b * LQ + t) * 4 + h) * 16;
    float4 p0 = *(const float4*)p;
    float4 p1 = *(const float4*)(p + 4);
    float4 p2 = *(const float4*)(p + 8);
    float4 p3 = *(const float4*)(p + 12);
    float a = (p0.x + p0.z) + (p1.x + p1.z) + (p2.x + p2.z) + (p3.x + p3.z);
    float l = (p0.y + p0.w) + (p1.y + p1.w) + (p2.y + p2.w) + (p3.y + p3.w);
    at[b][h * 2] = a / l;
    at[b][h * 2 + 1] = 1.f;
  }
  __syncthreads();
  const int q = tid >> 2, s = tid & 3;
  float wv[4][8], cg[4];
#pragma unroll
  for (int j = 0; j < 4; ++j) {
    int row = q * 4 + j;
    float4 a0 = *(const float4*)(fwc + row * 12);
    float4 a1 = *(const float4*)(fwc + row * 12 + 4);
    wv[j][0] = a0.x; wv[j][1] = a0.y; wv[j][2] = a0.z; wv[j][3] = a0.w;
    wv[j][4] = a1.x; wv[j][5] = a1.y; wv[j][6] = a1.z; wv[j][7] = a1.w;
    cg[j] = fwc[row * 12 + 8];
  }
  unsigned short* obase = xg + (((size_t)t * 96 + q) * 64 + s * 16) * 4;
#pragma unroll 4
  for (int bb = 0; bb < 16; ++bb) {
    const float* a = at[s * 16 + bb];
    u16x4 o;
#pragma unroll
    for (int j = 0; j < 4; ++j) {
      float acc = cg[j] + wv[j][0] * a[0] + wv[j][1] * a[1] + wv[j][2] * a[2] + wv[j][3] * a[3]
                        + wv[j][4] * a[4] + wv[j][5] * a[5] + wv[j][6] * a[6] + wv[j][7] * a[7];
      o[j] = f2bf(acc);
    }
    *(u16x4*)(obase + bb * 4) = o;
  }
}

// ---------------- fused attention v6: R11 structure + 8-way key split (2 blocks/CU) ----------------
__global__ __launch_bounds__(256, 2) void k_attn(
    const float* __restrict__ Xfa, const void* __restrict__ mraw,
    const float* __restrict__ fav,
    const float* __restrict__ kw, const float* __restrict__ kb,
    const float* __restrict__ lw, const float* __restrict__ lb,
    const float* __restrict__ pw, const float* __restrict__ pb,
    const unsigned short* __restrict__ qbf,
    float* __restrict__ part) {
  __shared__ unsigned short kwl[128 * 136];     // 4 heads x 32 rows, bf16
  __shared__ unsigned short ktl[2][64 * 136];   // projected K tile, double-buffered
  __shared__ float xt[2][64], mtl[2][64], kbl[128], Ac[128], Bc[128];
  __shared__ int sflag;

  const int tid = threadIdx.x;
  const int lane = tid & 63, wave = tid >> 6;
  const int l15 = lane & 15, kg = lane >> 4;
  const int b = blockIdx.x >> 3, qt = blockIdx.x & 7;
  const float KSCALE = 2.3873241463784303f;

  if (tid < 128) {
    Ac[tid] = (tid == 0) ? lw[0] : pw[tid - 1];
    Bc[tid] = (tid == 0) ? lb[0] : pb[tid - 1];
    kbl[tid] = kb[tid];
  }
  if (wave == 3) {
    const unsigned* raw = (const unsigned*)mraw;
    int isf = 0, isb = 0;
#pragma unroll
    for (int k = 0; k < 4; ++k) {
      unsigned w2 = raw[lane + k * 64];
      isf |= (w2 == 0x3F800000u);
      isb |= (w2 > 1u);
    }
    isf = __any(isf);
    isb = __any(isb);
    if (lane == 0) sflag = isf ? 2 : (isb ? 1 : 0);
  }
  for (int idx = tid; idx < 2048; idx += 256) {
    int d = idx >> 4, e0 = (idx & 15) * 8;
    const float* src = kw + d * 128 + e0;
    float4 s0 = *(const float4*)(src);
    float4 s1 = *(const float4*)(src + 4);
    bf16x8 v;
    v[0] = (short)f2bf(s0.x); v[1] = (short)f2bf(s0.y);
    v[2] = (short)f2bf(s0.z); v[3] = (short)f2bf(s0.w);
    v[4] = (short)f2bf(s1.x); v[5] = (short)f2bf(s1.y);
    v[6] = (short)f2bf(s1.z); v[7] = (short)f2bf(s1.w);
    *(bf16x8*)&kwl[d * 136 + e0] = v;
  }
  bf16x8 qa[4][2];
#pragma unroll
  for (int h = 0; h < 4; ++h)
#pragma unroll
    for (int mt = 0; mt < 2; ++mt) {
      int qrow = (wave * 2 + mt) * 16 + l15;
      qa[h][mt] = *(const bf16x8*)(qbf + (h * 128 + qrow) * 32 + kg * 8);
    }
  float sl[4][2][4], sa[4][2][4];
#pragma unroll
  for (int h = 0; h < 4; ++h)
#pragma unroll
    for (int mt = 0; mt < 2; ++mt)
#pragma unroll
      for (int r = 0; r < 4; ++r) { sl[h][mt][r] = 0.f; sa[h][mt][r] = 0.f; }
  __syncthreads();
  const int mfl = sflag;

  // STAGE(tile tt): embed own s-row in regs, project all heads into ktl[tt&1], stage x/mask-bias.
#define ATTN_STAGE(TT)                                                                   \
  {                                                                                      \
    const int tt_ = (TT);                                                                \
    const int ss0 = qt * 256 + tt_ * 64;                                                 \
    float tv = fav[b * SEQ + ss0 + wave * 16 + l15] * KSCALE;                            \
    float xfv = 0.f, mbv = 0.f;                                                          \
    if (tid < 64) {                                                                      \
      int gi = b * SEQ + ss0 + tid;                                                      \
      xfv = Xfa[gi];                                                                     \
      bool on;                                                                           \
      if (mfl == 2)      on = (((const float*)mraw)[gi] != 0.f);                         \
      else if (mfl == 1) on = (((const unsigned char*)mraw)[gi] != 0);                   \
      else               on = (((const int*)mraw)[gi] != 0);                             \
      mbv = on ? 0.f : -30000.f;                                                         \
    }                                                                                    \
    bf16x8 af[4];                                                                        \
    _Pragma("unroll")                                                                    \
    for (int kp = 0; kp < 4; ++kp) {                                                     \
      bf16x8 v;                                                                          \
      _Pragma("unroll")                                                                  \
      for (int j = 0; j < 8; ++j) {                                                      \
        int e = kp * 32 + kg * 8 + j;                                                    \
        float arg = fmaf(tv, Ac[e], Bc[e]);                                              \
        float val = (e == 0) ? arg : __sinf(arg);                                        \
        v[j] = (short)f2bf(val);                                                         \
      }                                                                                  \
      af[kp] = v;                                                                        \
    }                                                                                    \
    _Pragma("unroll")                                                                    \
    for (int h = 0; h < 4; ++h) {                                                        \
      _Pragma("unroll")                                                                  \
      for (int nt = 0; nt < 2; ++nt) {                                                   \
        f32x4 acc = {0.f, 0.f, 0.f, 0.f};                                                \
        _Pragma("unroll")                                                                \
        for (int kp = 0; kp < 4; ++kp) {                                                 \
          bf16x8 bb = *(const bf16x8*)&kwl[(h * 32 + nt * 16 + l15) * 136 + kp * 32 + kg * 8]; \
          acc = __builtin_amdgcn_mfma_f32_16x16x32_bf16(af[kp], bb, acc, 0, 0, 0);       \
        }                                                                                \
        int d = nt * 16 + l15;                                                           \
        float kbv = kbl[h * 32 + d];                                                     \
        _Pragma("unroll")                                                                \
        for (int r = 0; r < 4; ++r) {                                                    \
          int srow = wave * 16 + kg * 4 + r;                                             \
          ktl[tt_ & 1][srow * 136 + h * 32 + d] = f2bf(acc[r] + kbv);                    \
        }                                                                                \
      }                                                                                  \
    }                                                                                    \
    if (tid < 64) {                                                                      \
      xt[tt_ & 1][tid] = xfv;                                                            \
      mtl[tt_ & 1][tid] = mbv;                                                           \
    }                                                                                    \
  }

  ATTN_STAGE(0);
  softbar();
#pragma unroll 1
  for (int t8 = 0; t8 < 4; ++t8) {
    const int cur = t8 & 1;
    {
      float xv[4], mv[4];
#pragma unroll
      for (int nt2 = 0; nt2 < 4; ++nt2) {
        int scol = nt2 * 16 + l15;
        xv[nt2] = xt[cur][scol];
        mv[nt2] = mtl[cur][scol];
      }
#pragma unroll
      for (int h = 0; h < 4; ++h) {
        f32x4 D[2][4];
#pragma unroll
        for (int nt2 = 0; nt2 < 4; ++nt2) {
          int scol = nt2 * 16 + l15;
          bf16x8 bk = *(const bf16x8*)&ktl[cur][scol * 136 + h * 32 + kg * 8];
#pragma unroll
          for (int mt = 0; mt < 2; ++mt) {
            f32x4 z = {0.f, 0.f, 0.f, 0.f};
            D[mt][nt2] = __builtin_amdgcn_mfma_f32_16x16x32_bf16(qa[h][mt], bk, z, 0, 0, 0);
          }
        }
#pragma unroll
        for (int mt = 0; mt < 2; ++mt)
#pragma unroll
          for (int r = 0; r < 4; ++r) {
            float p0 = fexp2(D[mt][0][r] + mv[0]);
            float p1 = fexp2(D[mt][1][r] + mv[1]);
            float p2 = fexp2(D[mt][2][r] + mv[2]);
            float p3 = fexp2(D[mt][3][r] + mv[3]);
            sl[h][mt][r] += (p0 + p1) + (p2 + p3);
            sa[h][mt][r] += fmaf(p0, xv[0], fmaf(p1, xv[1], fmaf(p2, xv[2], p3 * xv[3])));
          }
      }
    }
    if (t8 < 3) ATTN_STAGE(t8 + 1);
    softbar();
  }
#undef ATTN_STAGE
#pragma unroll
  for (int h = 0; h < 4; ++h)
#pragma unroll
    for (int mt = 0; mt < 2; ++mt)
#pragma unroll
      for (int r = 0; r < 4; ++r) {
        float l = sl[h][mt][r], a = sa[h][mt][r];
#pragma unroll
        for (int off = 1; off <= 8; off <<= 1) {
          l += __shfl_xor(l, off);
          a += __shfl_xor(a, off);
        }
        if (l15 == 0) {
          int q = (wave * 2 + mt) * 16 + kg * 4 + r;
          float* p = part + ((size_t)(b * LQ + q) * 4 + h) * 16 + qt * 2;
          p[0] = a;
          p[1] = l;
        }
      }
}

// ---------------- GRU v11: C-folds, conflict-free hbf, per-step store ----------------
__global__ __launch_bounds__(512) void k_gru11(
    const float* __restrict__ whh, const float* __restrict__ bhh,
    const unsigned short* __restrict__ xg, unsigned short* __restrict__ gout) {
  __shared__ unsigned short hbf[2][16][132];
  const int tid = threadIdx.x;
  const int lane = tid & 63, w = tid >> 6;
  const int l15 = lane & 15, kg = lane >> 4;
  const int b0 = blockIdx.x * 16;

  for (int i = tid; i < 2 * 16 * 132 / 2; i += 512) ((unsigned*)hbf)[i] = 0u;

  bf16x8 wfr[3][4];
#pragma unroll
  for (int n = 0; n < 3; ++n) {
    const float sc = (n < 2) ? -1.4426950408889634f : 2.8853900817779268f;
    const float* wrow = whh + (n * 128 + w * 16 + l15) * 128 + kg * 8;
#pragma unroll
    for (int kk = 0; kk < 4; ++kk) {
      float4 f0 = *(const float4*)(wrow + kk * 32);
      float4 f1 = *(const float4*)(wrow + kk * 32 + 4);
      bf16x8 v;
      v[0] = (short)f2bf(f0.x * sc); v[1] = (short)f2bf(f0.y * sc);
      v[2] = (short)f2bf(f0.z * sc); v[3] = (short)f2bf(f0.w * sc);
      v[4] = (short)f2bf(f1.x * sc); v[5] = (short)f2bf(f1.y * sc);
      v[6] = (short)f2bf(f1.z * sc); v[7] = (short)f2bf(f1.w * sc);
      wfr[n][kk] = v;
    }
  }
  f32x4 bhnv;
  {
    float4 t = *(const float4*)(bhh + 256 + w * 16 + kg * 4);
    bhnv[0] = t.x * 2.8853900817779268f; bhnv[1] = t.y * 2.8853900817779268f;
    bhnv[2] = t.z * 2.8853900817779268f; bhnv[3] = t.w * 2.8853900817779268f;
  }
  float hold[4] = {0.f, 0.f, 0.f, 0.f};

  const unsigned short* xlane = xg + (((size_t)(w * 4 + kg)) * 64 + b0 + l15) * 4;
  unsigned short* gptr = gout + (size_t)(b0 + l15) * LQ * NH + w * 16 + kg * 4;

  u16x4 xA[2][3], xB[2][3];
#pragma unroll
  for (int s = 0; s < 2; ++s)
#pragma unroll
    for (int n = 0; n < 3; ++n)
      xA[s][n] = *(const u16x4*)(xlane + (size_t)s * 24576 + n * 8192);
  __syncthreads();

#define GRU_STEP(T, XQ)                                                                 \
  {                                                                                     \
    const int t_ = (T);                                                                 \
    bf16x8 hf[4];                                                                       \
    _Pragma("unroll")                                                                   \
    for (int kk = 0; kk < 4; ++kk)                                                      \
      hf[kk] = *(const bf16x8*)&hbf[t_ & 1][l15][kg * 8 + kk * 32];                     \
    f32x4 c0, c1;                                                                       \
    _Pragma("unroll")                                                                   \
    for (int r = 0; r < 4; ++r) { c0[r] = b2f(XQ[0][r]); c1[r] = b2f(XQ[1][r]); }       \
    f32x4 z4 = {0.f, 0.f, 0.f, 0.f};                                                    \
    f32x4 p0 = __builtin_amdgcn_mfma_f32_16x16x32_bf16(wfr[0][0], hf[0], c0, 0, 0, 0);  \
    p0 = __builtin_amdgcn_mfma_f32_16x16x32_bf16(wfr[0][1], hf[1], p0, 0, 0, 0);        \
    f32x4 q0 = __builtin_amdgcn_mfma_f32_16x16x32_bf16(wfr[0][2], hf[2], z4, 0, 0, 0);  \
    q0 = __builtin_amdgcn_mfma_f32_16x16x32_bf16(wfr[0][3], hf[3], q0, 0, 0, 0);        \
    f32x4 p1 = __builtin_amdgcn_mfma_f32_16x16x32_bf16(wfr[1][0], hf[0], c1, 0, 0, 0);  \
    p1 = __builtin_amdgcn_mfma_f32_16x16x32_bf16(wfr[1][1], hf[1], p1, 0, 0, 0);        \
    f32x4 q1 = __builtin_amdgcn_mfma_f32_16x16x32_bf16(wfr[1][2], hf[2], z4, 0, 0, 0);  \
    q1 = __builtin_amdgcn_mfma_f32_16x16x32_bf16(wfr[1][3], hf[3], q1, 0, 0, 0);        \
    f32x4 p2 = __builtin_amdgcn_mfma_f32_16x16x32_bf16(wfr[2][0], hf[0], bhnv, 0, 0, 0);\
    p2 = __builtin_amdgcn_mfma_f32_16x16x32_bf16(wfr[2][1], hf[1], p2, 0, 0, 0);        \
    f32x4 q2 = __builtin_amdgcn_mfma_f32_16x16x32_bf16(wfr[2][2], hf[2], z4, 0, 0, 0);  \
    q2 = __builtin_amdgcn_mfma_f32_16x16x32_bf16(wfr[2][3], hf[3], q2, 0, 0, 0);        \
    f32x4 a0 = p0 + q0, a1 = p1 + q1, a2 = p2 + q2;                                     \
    float hv[4];                                                                        \
    _Pragma("unroll")                                                                   \
    for (int r = 0; r < 4; ++r) {                                                       \
      float R = frcp(1.f + fexp2(a0[r]));                                               \
      float Z = frcp(1.f + fexp2(a1[r]));                                               \
      float u = fmaf(R, a2[r], b2f(XQ[2][r]));                                          \
      float Tt = frcp(1.f + fexp2(u));                                                  \
      float ng = fmaf(-2.f, Tt, 1.f);                                                   \
      float hn = fmaf(Z, hold[r] - ng, ng);                                             \
      hold[r] = hn;                                                                     \
      hv[r] = hn;                                                                       \
    }                                                                                   \
    uint2v d;                                                                           \
    d[0] = cvtpk(hv[0], hv[1]);                                                         \
    d[1] = cvtpk(hv[2], hv[3]);                                                         \
    *(uint2v*)&hbf[(t_ & 1) ^ 1][l15][w * 16 + kg * 4] = d;                             \
    *(uint2v*)(gptr + (size_t)t_ * NH) = d;                                             \
    softbar();                                                                          \
  }

#define GRU_PAIR(TP, XC, XN)                                                            \
  {                                                                                     \
    const int tp_ = (TP);                                                               \
    const int tl = (tp_ < 63) ? (tp_ + 1) : 63;                                         \
    _Pragma("unroll")                                                                   \
    for (int s = 0; s < 2; ++s)                                                         \
      _Pragma("unroll")                                                                 \
      for (int n = 0; n < 3; ++n)                                                       \
        XN[s][n] = *(const u16x4*)(xlane + ((size_t)(tl * 2 + s)) * 24576 + n * 8192);  \
    GRU_STEP(tp_ * 2, XC[0]);                                                           \
    GRU_STEP(tp_ * 2 + 1, XC[1]);                                                       \
  }

#pragma unroll 1
  for (int tp = 0; tp < 64; tp += 2) {
    GRU_PAIR(tp, xA, xB);
    GRU_PAIR(tp + 1, xB, xA);
  }
#undef GRU_PAIR
#undef GRU_STEP
}

// ---------------- pooling + MLP heads + signal equation ----------------
__global__ __launch_bounds__(256) void k_heads(
    const unsigned short* __restrict__ gout,
    const float* __restrict__ swT, const float* __restrict__ swM,
    const float* __restrict__ tw1, const float* __restrict__ tb1,
    const float* __restrict__ tw2, const float* __restrict__ tb2,
    const float* __restrict__ tw3, const float* __restrict__ tb3,
    const float* __restrict__ mw1, const float* __restrict__ mb1,
    const float* __restrict__ mw2, const float* __restrict__ mb2,
    const float* __restrict__ mw3, const float* __restrict__ mb3,
    const float* __restrict__ fav, const float* __restrict__ TRv,
    float* __restrict__ out) {
  __shared__ float hbuf[128 * 129];
  __shared__ float pp[2][128][2];
  __shared__ float pT[128], pM[128];
  __shared__ float hidT[128], hidM[128];
  __shared__ float l1b[200], l2b[200];
  __shared__ float parts[4];
  __shared__ float scal[2];
  const int tid = threadIdx.x;
  const int b = blockIdx.x;
#pragma unroll
  for (int rep = 0; rep < 8; ++rep) {
    int idx = rep * 2048 + tid * 8;
    int row = idx >> 7, col = idx & 127;
    bf16x8 v = *(const bf16x8*)(gout + (size_t)b * (LQ * NH) + idx);
#pragma unroll
    for (int j = 0; j < 8; ++j)
      hbuf[row * 129 + col + j] = b2f((unsigned short)v[j]);
  }
  __syncthreads();
  {
    int t = tid & 127, hf2 = tid >> 7;
    float aT = 0.f, aM = 0.f;
    for (int j = 0; j < 64; ++j) {
      float v = hbuf[t * 129 + hf2 * 64 + j];
      aT = fmaf(v, swT[hf2 * 64 + j], aT);
      aM = fmaf(v, swM[hf2 * 64 + j], aM);
    }
    pp[hf2][t][0] = aT;
    pp[hf2][t][1] = aM;
  }
  __syncthreads();
  if (tid < 64) {
    float v0 = pp[0][tid][0] + pp[1][tid][0];
    float v1 = pp[0][tid + 64][0] + pp[1][tid + 64][0];
    float m = fmaxf(v0, v1);
    for (int off = 32; off > 0; off >>= 1) m = fmaxf(m, __shfl_xor(m, off));
    float p0 = __expf(v0 - m), p1 = __expf(v1 - m);
    float s = p0 + p1;
    for (int off = 32; off > 0; off >>= 1) s += __shfl_xor(s, off);
    float inv = 1.f / s;
    pT[tid] = p0 * inv; pT[tid + 64] = p1 * inv;
  } else if (tid < 128) {
    int l = tid - 64;
    float v0 = pp[0][l][1] + pp[1][l][1];
    float v1 = pp[0][l + 64][1] + pp[1][l + 64][1];
    float m = fmaxf(v0, v1);
    for (int off = 32; off > 0; off >>= 1) m = fmaxf(m, __shfl_xor(m, off));
    float p0 = __expf(v0 - m), p1 = __expf(v1 - m);
    float s = p0 + p1;
    for (int off = 32; off > 0; off >>= 1) s += __shfl_xor(s, off);
    float inv = 1.f / s;
    pM[l] = p0 * inv; pM[l + 64] = p1 * inv;
  }
  __syncthreads();
  {
    int j = tid & 127, hf2 = tid >> 7;
    float aT = 0.f, aM = 0.f;
    for (int t2 = 0; t2 < 64; ++t2) {
      int t = hf2 * 64 + t2;
      float v = hbuf[t * 129 + j];
      aT = fmaf(v, pT[t], aT);
      aM = fmaf(v, pM[t], aM);
    }
    pp[hf2][j][0] = aT;
    pp[hf2][j][1] = aM;
  }
  __syncthreads();
  if (tid < 128) {
    hidT[tid] = pp[0][tid][0] + pp[1][tid][0];
    hidM[tid] = pp[0][tid][1] + pp[1][tid][1];
  }
  __syncthreads();
#pragma unroll 1
  for (int hd = 0; hd < 2; ++hd) {
    const float* in = hd ? hidM : hidT;
    const float* w1 = hd ? mw1 : tw1; const float* b1 = hd ? mb1 : tb1;
    const float* w2 = hd ? mw2 : tw2; const float* b2 = hd ? mb2 : tb2;
    const float* w3 = hd ? mw3 : tw3; const float* b3 = hd ? mb3 : tb3;
    if (tid < 200) {
      float acc = b1[tid];
      for (int j4 = 0; j4 < 32; ++j4) {
        float4 wv = *(const float4*)(w1 + tid * 128 + j4 * 4);
        acc += wv.x * in[j4 * 4] + wv.y * in[j4 * 4 + 1] + wv.z * in[j4 * 4 + 2] + wv.w * in[j4 * 4 + 3];
      }
      l1b[tid] = gelu_f(acc);
    }
    __syncthreads();
    if (tid < 200) {
      float acc = b2[tid];
      for (int k4 = 0; k4 < 50; ++k4) {
        float4 wv = *(const float4*)(w2 + tid * 200 + k4 * 4);
        acc += wv.x * l1b[k4 * 4] + wv.y * l1b[k4 * 4 + 1] + wv.z * l1b[k4 * 4 + 2] + wv.w * l1b[k4 * 4 + 3];
      }
      l2b[tid] = gelu_f(acc);
    }
    __syncthreads();
    float part = (tid < 200) ? l2b[tid] * w3[tid] : 0.f;
    for (int off = 32; off > 0; off >>= 1) part += __shfl_xor(part, off);
    if ((tid & 63) == 0) parts[tid >> 6] = part;
    __syncthreads();
    if (tid == 0) {
      float y = parts[0] + parts[1] + parts[2] + parts[3] + b3[0];
      float hi = hd ? 10.f : 5.f;
      float val = 0.1f + sigm(y) * (hi - 0.1f);
      scal[hd] = val;
      out[BS * SEQ + hd * BS + b] = val;
    }
    __syncthreads();
  }
  float T10 = scal[0], M0 = scal[1];
  float R1 = 1.f / T10;
  for (int i = tid; i < SEQ; i += 256) {
    float fa = fav[b * SEQ + i];
    float tr = TRv[b * SEQ + i];
    float E = __expf(-tr * R1);
    float s, c;
    __sincosf(fa, &s, &c);
    out[b * SEQ + i] = (1.f - E) * s / (1.f - c * E) * M0;
  }
}

// ---------------- launch ----------------
extern "C" void kernel_launch(void* const* d_in, const int* in_sizes, int n_in,
                              void* d_out, int out_size, void* d_ws, size_t ws_size,
                              hipStream_t stream) {
  const float* Xfa = (const float*)d_in[0];
  const float* fav = (const float*)d_in[1];
  const void*  mraw = d_in[2];
  const float* TRv = (const float*)d_in[4];
  const float* lw = (const float*)d_in[5];
  const float* lb = (const float*)d_in[6];
  const float* pw = (const float*)d_in[7];
  const float* pb = (const float*)d_in[8];
  const float* qw = (const float*)d_in[9];
  const float* qb = (const float*)d_in[10];
  const float* kw = (const float*)d_in[11];
  const float* kb = (const float*)d_in[12];
  const float* aow = (const float*)d_in[13];
  const float* aob = (const float*)d_in[14];
  const float* wih = (const float*)d_in[15];
  const float* whh = (const float*)d_in[16];
  const float* bih = (const float*)d_in[17];
  const float* bhh = (const float*)d_in[18];
  const float* swT = (const float*)d_in[19];
  const float* swM = (const float*)d_in[20];
  const float* tw1 = (const float*)d_in[21];
  const float* tb1 = (const float*)d_in[22];
  const float* tw2 = (const float*)d_in[23];
  const float* tb2 = (const float*)d_in[24];
  const float* tw3 = (const float*)d_in[25];
  const float* tb3 = (const float*)d_in[26];
  const float* mw1 = (const float*)d_in[27];
  const float* mb1 = (const float*)d_in[28];
  const float* mw2 = (const float*)d_in[29];
  const float* mb2 = (const float*)d_in[30];
  const float* mw3 = (const float*)d_in[31];
  const float* mb3 = (const float*)d_in[32];
  float* out = (float*)d_out;
  char* ws = (char*)d_ws;

  unsigned short* qbf = (unsigned short*)ws;              // 0       .. 32768
  float* part = (float*)(ws + 32768);                     // 2 MB (aliases gout; dead before gru writes)
  unsigned short* gout = (unsigned short*)(ws + 32768);   // 2 MB    .. 2129920
  float* fwc = (float*)(ws + 2129920);                    //         .. 2148352
  unsigned short* xgate = (unsigned short*)(ws + 2148352);// 6.29 MB .. 8439808

  k_prep<<<9, 384, 0, stream>>>(qw, qb, lw, lb, pw, pb,
                                wih, bih, bhh, aow, aob, qbf, fwc);
  k_attn<<<512, 256, 0, stream>>>(Xfa, mraw, fav, kw, kb, lw, lb, pw, pb, qbf, part);
  k_xgate<<<128, 384, 0, stream>>>(fwc, part, xgate);
  k_gru11<<<4, 512, 0, stream>>>(whh, bhh, xgate, gout);
  k_heads<<<64, 256, 0, stream>>>(gout, swT, swM, tw1, tb1, tw2, tb2, tw3, tb3,
                                  mw1, mb1, mw2, mb2, mw3, mb3, fav, TRv, out);
}

// Round 14
// 179.103 us; speedup vs baseline: 1.0334x; 1.0334x over previous
//
#include <hip/hip_runtime.h>

#define BS 64
#define SEQ 2048
#define LQ 128
#define NH 128

typedef short bf16x8 __attribute__((ext_vector_type(8)));
typedef float f32x4 __attribute__((ext_vector_type(4)));
typedef unsigned short u16x4 __attribute__((ext_vector_type(4)));
typedef unsigned uint2v __attribute__((ext_vector_type(2)));

__device__ __forceinline__ unsigned short f2bf(float f) {
  unsigned u = __float_as_uint(f);
  u = (u + 0x7FFFu + ((u >> 16) & 1u)) >> 16;
  return (unsigned short)u;
}
__device__ __forceinline__ float b2f(unsigned short u) {
  return __uint_as_float((unsigned)u << 16);
}
__device__ __forceinline__ float sigm(float x) { return 1.f / (1.f + __expf(-x)); }
__device__ __forceinline__ float gelu_f(float x) { return 0.5f * x * (1.f + erff(x * 0.70710678118654752f)); }
__device__ __forceinline__ float fexp2(float x) { float y; asm("v_exp_f32 %0, %1" : "=v"(y) : "v"(x)); return y; }
__device__ __forceinline__ float frcp(float x) { float y; asm("v_rcp_f32 %0, %1" : "=v"(y) : "v"(x)); return y; }
__device__ __forceinline__ unsigned cvtpk(float lo, float hi) {
  unsigned d; asm("v_cvt_pk_bf16_f32 %0, %1, %2" : "=v"(d) : "v"(lo), "v"(hi)); return d;
}

// LDS-only barrier (no vmcnt drain at source level).
__device__ __forceinline__ void softbar() {
  asm volatile("s_waitcnt lgkmcnt(0)" ::: "memory");
  __builtin_amdgcn_s_barrier();
  __builtin_amdgcn_sched_barrier(0);
}

// ---------------- prep: q-proj (C2-scaled) + fold (9 blocks) ----------------
__global__ __launch_bounds__(384) void k_prep(
    const float* __restrict__ qw, const float* __restrict__ qb,
    const float* __restrict__ lw, const float* __restrict__ lb,
    const float* __restrict__ pw, const float* __restrict__ pb,
    const float* __restrict__ wih, const float* __restrict__ bih,
    const float* __restrict__ bhh,
    const float* __restrict__ aow, const float* __restrict__ aob,
    unsigned short* __restrict__ qbf, float* __restrict__ fwc) {
  const int tid = threadIdx.x;
  const int blk = blockIdx.x;
  if (blk < 8) {
    __shared__ float emb[16 * 132];
    __shared__ float Ac[128], Bc[128];
    const float C2 = 0.25505654f;  // log2(e)/sqrt(32), folded into q
    if (tid < 128) {
      Ac[tid] = (tid == 0) ? lw[0] : pw[tid - 1];
      Bc[tid] = (tid == 0) ? lb[0] : pb[tid - 1];
    }
    __syncthreads();
    if (tid < 256) {
      int lq = tid >> 4, e0 = (tid & 15) * 8;
      float tv = (float)(blk * 16 + lq) * (1.f / 127.f);
#pragma unroll
      for (int k = 0; k < 8; ++k) {
        int e = e0 + k;
        float arg = fmaf(tv, Ac[e], Bc[e]);
        emb[lq * 132 + e] = (e == 0) ? arg : __sinf(arg);
      }
    }
    __syncthreads();
    if (tid < 256) {
      const int c = tid & 127, lh = tid >> 7;
      float acc[8];
#pragma unroll
      for (int i = 0; i < 8; ++i) acc[i] = qb[c];
      for (int e4 = 0; e4 < 32; ++e4) {
        float4 wv = *(const float4*)(qw + c * 128 + e4 * 4);
#pragma unroll
        for (int i = 0; i < 8; ++i) {
          const float* er = &emb[(lh * 8 + i) * 132 + e4 * 4];
          acc[i] += wv.x * er[0] + wv.y * er[1] + wv.z * er[2] + wv.w * er[3];
        }
      }
#pragma unroll
      for (int i = 0; i < 8; ++i) {
        int lq = blk * 16 + lh * 8 + i;
        qbf[((c >> 5) * LQ + lq) * 32 + (c & 31)] = f2bf(acc[i] * C2);
      }
    }
  } else {
    const int g = tid;
    const float sc = (g < 256) ? -1.4426950408889634f : 2.8853900817779268f;
    float fw[8];
#pragma unroll
    for (int c = 0; c < 8; ++c) fw[c] = 0.f;
    float cg = bih[g] + (g < 256 ? bhh[g] : 0.f);
    for (int j = 0; j < 128; ++j) {
      float w = wih[g * 128 + j];
      cg = fmaf(w, aob[j], cg);
#pragma unroll
      for (int c = 0; c < 8; ++c) fw[c] = fmaf(w, aow[j * 8 + c], fw[c]);
    }
#pragma unroll
    for (int c = 0; c < 8; ++c) fwc[g * 12 + c] = fw[c] * sc;
    fwc[g * 12 + 8] = cg * sc;
  }
}

// ---------------- x-gates: xg[t][quad=96][b=64][4] bf16 (gru-coalesced) ----------------
__global__ __launch_bounds__(384) void k_xgate(
    const float* __restrict__ fwc, const float* __restrict__ part,
    unsigned short* __restrict__ xg) {
  __shared__ float at[64][8];
  const int tid = threadIdx.x;
  const int t = blockIdx.x;
  if (tid < 256) {
    int b = tid >> 2, h = tid & 3;
    const float* p = part + ((size_t)(b * LQ + t) * 4 + h) * 8;
    float4 p0 = *(const float4*)p;
    float4 p1 = *(const float4*)(p + 4);
    float a = p0.x + p0.z + p1.x + p1.z;
    float l = p0.y + p0.w + p1.y + p1.w;
    at[b][h * 2] = a / l;
    at[b][h * 2 + 1] = 1.f;
  }
  __syncthreads();
  const int q = tid >> 2, s = tid & 3;
  float wv[4][8], cg[4];
#pragma unroll
  for (int j = 0; j < 4; ++j) {
    int row = q * 4 + j;
    float4 a0 = *(const float4*)(fwc + row * 12);
    float4 a1 = *(const float4*)(fwc + row * 12 + 4);
    wv[j][0] = a0.x; wv[j][1] = a0.y; wv[j][2] = a0.z; wv[j][3] = a0.w;
    wv[j][4] = a1.x; wv[j][5] = a1.y; wv[j][6] = a1.z; wv[j][7] = a1.w;
    cg[j] = fwc[row * 12 + 8];
  }
  unsigned short* obase = xg + (((size_t)t * 96 + q) * 64 + s * 16) * 4;
#pragma unroll 4
  for (int bb = 0; bb < 16; ++bb) {
    const float* a = at[s * 16 + bb];
    u16x4 o;
#pragma unroll
    for (int j = 0; j < 4; ++j) {
      float acc = cg[j] + wv[j][0] * a[0] + wv[j][1] * a[1] + wv[j][2] * a[2] + wv[j][3] * a[3]
                        + wv[j][4] * a[4] + wv[j][5] * a[5] + wv[j][6] * a[6] + wv[j][7] * a[7];
      o[j] = f2bf(acc);
    }
    *(u16x4*)(obase + bb * 4) = o;
  }
}

// ---------------- fused attention v4: inline mask detect+bias, dbuf ktl, 1 barrier/tile ----------------
__global__ __launch_bounds__(256) void k_attn(
    const float* __restrict__ Xfa, const void* __restrict__ mraw,
    const float* __restrict__ fav,
    const float* __restrict__ kw, const float* __restrict__ kb,
    const float* __restrict__ lw, const float* __restrict__ lb,
    const float* __restrict__ pw, const float* __restrict__ pb,
    const unsigned short* __restrict__ qbf,
    float* __restrict__ part) {
  __shared__ unsigned short kwl[128 * 136];     // 4 heads x 32 rows, bf16
  __shared__ unsigned short ktl[2][64 * 136];   // projected K tile, double-buffered
  __shared__ float xt[2][64], mtl[2][64], kbl[128], Ac[128], Bc[128];
  __shared__ int sflag;

  const int tid = threadIdx.x;
  const int lane = tid & 63, wave = tid >> 6;
  const int l15 = lane & 15, kg = lane >> 4;
  const int b = blockIdx.x >> 2, qt = blockIdx.x & 3;
  const float KSCALE = 2.3873241463784303f;

  if (tid < 128) {
    Ac[tid] = (tid == 0) ? lw[0] : pw[tid - 1];
    Bc[tid] = (tid == 0) ? lb[0] : pb[tid - 1];
    kbl[tid] = kb[tid];
  }
  if (wave == 3) {
    const unsigned* raw = (const unsigned*)mraw;
    int isf = 0, isb = 0;
#pragma unroll
    for (int k = 0; k < 4; ++k) {
      unsigned w2 = raw[lane + k * 64];
      isf |= (w2 == 0x3F800000u);
      isb |= (w2 > 1u);
    }
    isf = __any(isf);
    isb = __any(isb);
    if (lane == 0) sflag = isf ? 2 : (isb ? 1 : 0);
  }
  for (int idx = tid; idx < 2048; idx += 256) {
    int d = idx >> 4, e0 = (idx & 15) * 8;
    const float* src = kw + d * 128 + e0;
    float4 s0 = *(const float4*)(src);
    float4 s1 = *(const float4*)(src + 4);
    bf16x8 v;
    v[0] = (short)f2bf(s0.x); v[1] = (short)f2bf(s0.y);
    v[2] = (short)f2bf(s0.z); v[3] = (short)f2bf(s0.w);
    v[4] = (short)f2bf(s1.x); v[5] = (short)f2bf(s1.y);
    v[6] = (short)f2bf(s1.z); v[7] = (short)f2bf(s1.w);
    *(bf16x8*)&kwl[d * 136 + e0] = v;
  }
  bf16x8 qa[4][2];
#pragma unroll
  for (int h = 0; h < 4; ++h)
#pragma unroll
    for (int mt = 0; mt < 2; ++mt) {
      int qrow = (wave * 2 + mt) * 16 + l15;
      qa[h][mt] = *(const bf16x8*)(qbf + (h * 128 + qrow) * 32 + kg * 8);
    }
  float sl[4][2][4], sa[4][2][4];
#pragma unroll
  for (int h = 0; h < 4; ++h)
#pragma unroll
    for (int mt = 0; mt < 2; ++mt)
#pragma unroll
      for (int r = 0; r < 4; ++r) { sl[h][mt][r] = 0.f; sa[h][mt][r] = 0.f; }
  __syncthreads();
  const int mfl = sflag;

  // STAGE(tile tt): embed own s-row in regs, project all heads into ktl[tt&1], stage x/mask-bias.
#define ATTN_STAGE(TT)                                                                   \
  {                                                                                      \
    const int tt_ = (TT);                                                                \
    const int ss0 = qt * 512 + tt_ * 64;                                                 \
    float tv = fav[b * SEQ + ss0 + wave * 16 + l15] * KSCALE;                            \
    float xfv = 0.f, mbv = 0.f;                                                          \
    if (tid < 64) {                                                                      \
      int gi = b * SEQ + ss0 + tid;                                                      \
      xfv = Xfa[gi];                                                                     \
      bool on;                                                                           \
      if (mfl == 2)      on = (((const float*)mraw)[gi] != 0.f);                         \
      else if (mfl == 1) on = (((const unsigned char*)mraw)[gi] != 0);                   \
      else               on = (((const int*)mraw)[gi] != 0);                             \
      mbv = on ? 0.f : -30000.f;                                                         \
    }                                                                                    \
    bf16x8 af[4];                                                                        \
    _Pragma("unroll")                                                                    \
    for (int kp = 0; kp < 4; ++kp) {                                                     \
      bf16x8 v;                                                                          \
      _Pragma("unroll")                                                                  \
      for (int j = 0; j < 8; ++j) {                                                      \
        int e = kp * 32 + kg * 8 + j;                                                    \
        float arg = fmaf(tv, Ac[e], Bc[e]);                                              \
        float val = (e == 0) ? arg : __sinf(arg);                                        \
        v[j] = (short)f2bf(val);                                                         \
      }                                                                                  \
      af[kp] = v;                                                                        \
    }                                                                                    \
    _Pragma("unroll")                                                                    \
    for (int h = 0; h < 4; ++h) {                                                        \
      _Pragma("unroll")                                                                  \
      for (int nt = 0; nt < 2; ++nt) {                                                   \
        f32x4 acc = {0.f, 0.f, 0.f, 0.f};                                                \
        _Pragma("unroll")                                                                \
        for (int kp = 0; kp < 4; ++kp) {                                                 \
          bf16x8 bb = *(const bf16x8*)&kwl[(h * 32 + nt * 16 + l15) * 136 + kp * 32 + kg * 8]; \
          acc = __builtin_amdgcn_mfma_f32_16x16x32_bf16(af[kp], bb, acc, 0, 0, 0);       \
        }                                                                                \
        int d = nt * 16 + l15;                                                           \
        float kbv = kbl[h * 32 + d];                                                     \
        _Pragma("unroll")                                                                \
        for (int r = 0; r < 4; ++r) {                                                    \
          int srow = wave * 16 + kg * 4 + r;                                             \
          ktl[tt_ & 1][srow * 136 + h * 32 + d] = f2bf(acc[r] + kbv);                    \
        }                                                                                \
      }                                                                                  \
    }                                                                                    \
    if (tid < 64) {                                                                      \
      xt[tt_ & 1][tid] = xfv;                                                            \
      mtl[tt_ & 1][tid] = mbv;                                                           \
    }                                                                                    \
  }

  ATTN_STAGE(0);
  softbar();
#pragma unroll 1
  for (int t8 = 0; t8 < 8; ++t8) {
    const int cur = t8 & 1;
    {
      float xv[4], mv[4];
#pragma unroll
      for (int nt2 = 0; nt2 < 4; ++nt2) {
        int scol = nt2 * 16 + l15;
        xv[nt2] = xt[cur][scol];
        mv[nt2] = mtl[cur][scol];
      }
#pragma unroll
      for (int h = 0; h < 4; ++h) {
        f32x4 D[2][4];
#pragma unroll
        for (int nt2 = 0; nt2 < 4; ++nt2) {
          int scol = nt2 * 16 + l15;
          bf16x8 bk = *(const bf16x8*)&ktl[cur][scol * 136 + h * 32 + kg * 8];
#pragma unroll
          for (int mt = 0; mt < 2; ++mt) {
            f32x4 z = {0.f, 0.f, 0.f, 0.f};
            D[mt][nt2] = __builtin_amdgcn_mfma_f32_16x16x32_bf16(qa[h][mt], bk, z, 0, 0, 0);
          }
        }
#pragma unroll
        for (int mt = 0; mt < 2; ++mt)
#pragma unroll
          for (int r = 0; r < 4; ++r) {
            float p0 = fexp2(D[mt][0][r] + mv[0]);
            float p1 = fexp2(D[mt][1][r] + mv[1]);
            float p2 = fexp2(D[mt][2][r] + mv[2]);
            float p3 = fexp2(D[mt][3][r] + mv[3]);
            sl[h][mt][r] += (p0 + p1) + (p2 + p3);
            sa[h][mt][r] += fmaf(p0, xv[0], fmaf(p1, xv[1], fmaf(p2, xv[2], p3 * xv[3])));
          }
      }
    }
    if (t8 < 7) ATTN_STAGE(t8 + 1);
    softbar();
  }
#undef ATTN_STAGE
#pragma unroll
  for (int h = 0; h < 4; ++h)
#pragma unroll
    for (int mt = 0; mt < 2; ++mt)
#pragma unroll
      for (int r = 0; r < 4; ++r) {
        float l = sl[h][mt][r], a = sa[h][mt][r];
#pragma unroll
        for (int off = 1; off <= 8; off <<= 1) {
          l += __shfl_xor(l, off);
          a += __shfl_xor(a, off);
        }
        if (l15 == 0) {
          int q = (wave * 2 + mt) * 16 + kg * 4 + r;
          float* p = part + ((size_t)(b * LQ + q) * 4 + h) * 8 + qt * 2;
          p[0] = a;
          p[1] = l;
        }
      }
}

// ---------------- GRU v11: C-folds, conflict-free hbf, per-step store ----------------
__global__ __launch_bounds__(512) void k_gru11(
    const float* __restrict__ whh, const float* __restrict__ bhh,
    const unsigned short* __restrict__ xg, unsigned short* __restrict__ gout) {
  __shared__ unsigned short hbf[2][16][132];
  const int tid = threadIdx.x;
  const int lane = tid & 63, w = tid >> 6;
  const int l15 = lane & 15, kg = lane >> 4;
  const int b0 = blockIdx.x * 16;

  for (int i = tid; i < 2 * 16 * 132 / 2; i += 512) ((unsigned*)hbf)[i] = 0u;

  bf16x8 wfr[3][4];
#pragma unroll
  for (int n = 0; n < 3; ++n) {
    const float sc = (n < 2) ? -1.4426950408889634f : 2.8853900817779268f;
    const float* wrow = whh + (n * 128 + w * 16 + l15) * 128 + kg * 8;
#pragma unroll
    for (int kk = 0; kk < 4; ++kk) {
      float4 f0 = *(const float4*)(wrow + kk * 32);
      float4 f1 = *(const float4*)(wrow + kk * 32 + 4);
      bf16x8 v;
      v[0] = (short)f2bf(f0.x * sc); v[1] = (short)f2bf(f0.y * sc);
      v[2] = (short)f2bf(f0.z * sc); v[3] = (short)f2bf(f0.w * sc);
      v[4] = (short)f2bf(f1.x * sc); v[5] = (short)f2bf(f1.y * sc);
      v[6] = (short)f2bf(f1.z * sc); v[7] = (short)f2bf(f1.w * sc);
      wfr[n][kk] = v;
    }
  }
  f32x4 bhnv;
  {
    float4 t = *(const float4*)(bhh + 256 + w * 16 + kg * 4);
    bhnv[0] = t.x * 2.8853900817779268f; bhnv[1] = t.y * 2.8853900817779268f;
    bhnv[2] = t.z * 2.8853900817779268f; bhnv[3] = t.w * 2.8853900817779268f;
  }
  float hold[4] = {0.f, 0.f, 0.f, 0.f};

  const unsigned short* xlane = xg + (((size_t)(w * 4 + kg)) * 64 + b0 + l15) * 4;
  unsigned short* gptr = gout + (size_t)(b0 + l15) * LQ * NH + w * 16 + kg * 4;

  u16x4 xA[2][3], xB[2][3];
#pragma unroll
  for (int s = 0; s < 2; ++s)
#pragma unroll
    for (int n = 0; n < 3; ++n)
      xA[s][n] = *(const u16x4*)(xlane + (size_t)s * 24576 + n * 8192);
  __syncthreads();

#define GRU_STEP(T, XQ)                                                                 \
  {                                                                                     \
    const int t_ = (T);                                                                 \
    bf16x8 hf[4];                                                                       \
    _Pragma("unroll")                                                                   \
    for (int kk = 0; kk < 4; ++kk)                                                      \
      hf[kk] = *(const bf16x8*)&hbf[t_ & 1][l15][kg * 8 + kk * 32];                     \
    f32x4 c0, c1;                                                                       \
    _Pragma("unroll")                                                                   \
    for (int r = 0; r < 4; ++r) { c0[r] = b2f(XQ[0][r]); c1[r] = b2f(XQ[1][r]); }       \
    f32x4 z4 = {0.f, 0.f, 0.f, 0.f};                                                    \
    f32x4 p0 = __builtin_amdgcn_mfma_f32_16x16x32_bf16(wfr[0][0], hf[0], c0, 0, 0, 0);  \
    p0 = __builtin_amdgcn_mfma_f32_16x16x32_bf16(wfr[0][1], hf[1], p0, 0, 0, 0);        \
    f32x4 q0 = __builtin_amdgcn_mfma_f32_16x16x32_bf16(wfr[0][2], hf[2], z4, 0, 0, 0);  \
    q0 = __builtin_amdgcn_mfma_f32_16x16x32_bf16(wfr[0][3], hf[3], q0, 0, 0, 0);        \
    f32x4 p1 = __builtin_amdgcn_mfma_f32_16x16x32_bf16(wfr[1][0], hf[0], c1, 0, 0, 0);  \
    p1 = __builtin_amdgcn_mfma_f32_16x16x32_bf16(wfr[1][1], hf[1], p1, 0, 0, 0);        \
    f32x4 q1 = __builtin_amdgcn_mfma_f32_16x16x32_bf16(wfr[1][2], hf[2], z4, 0, 0, 0);  \
    q1 = __builtin_amdgcn_mfma_f32_16x16x32_bf16(wfr[1][3], hf[3], q1, 0, 0, 0);        \
    f32x4 p2 = __builtin_amdgcn_mfma_f32_16x16x32_bf16(wfr[2][0], hf[0], bhnv, 0, 0, 0);\
    p2 = __builtin_amdgcn_mfma_f32_16x16x32_bf16(wfr[2][1], hf[1], p2, 0, 0, 0);        \
    f32x4 q2 = __builtin_amdgcn_mfma_f32_16x16x32_bf16(wfr[2][2], hf[2], z4, 0, 0, 0);  \
    q2 = __builtin_amdgcn_mfma_f32_16x16x32_bf16(wfr[2][3], hf[3], q2, 0, 0, 0);        \
    f32x4 a0 = p0 + q0, a1 = p1 + q1, a2 = p2 + q2;                                     \
    float hv[4];                                                                        \
    _Pragma("unroll")                                                                   \
    for (int r = 0; r < 4; ++r) {                                                       \
      float R = frcp(1.f + fexp2(a0[r]));                                               \
      float Z = frcp(1.f + fexp2(a1[r]));                                               \
      float u = fmaf(R, a2[r], b2f(XQ[2][r]));                                          \
      float Tt = frcp(1.f + fexp2(u));                                                  \
      float ng = fmaf(-2.f, Tt, 1.f);                                                   \
      float hn = fmaf(Z, hold[r] - ng, ng);                                             \
      hold[r] = hn;                                                                     \
      hv[r] = hn;                                                                       \
    }                                                                                   \
    uint2v d;                                                                           \
    d[0] = cvtpk(hv[0], hv[1]);                                                         \
    d[1] = cvtpk(hv[2], hv[3]);                                                         \
    *(uint2v*)&hbf[(t_ & 1) ^ 1][l15][w * 16 + kg * 4] = d;                             \
    *(uint2v*)(gptr + (size_t)t_ * NH) = d;                                             \
    softbar();                                                                          \
  }

#define GRU_PAIR(TP, XC, XN)                                                            \
  {                                                                                     \
    const int tp_ = (TP);                                                               \
    const int tl = (tp_ < 63) ? (tp_ + 1) : 63;                                         \
    _Pragma("unroll")                                                                   \
    for (int s = 0; s < 2; ++s)                                                         \
      _Pragma("unroll")                                                                 \
      for (int n = 0; n < 3; ++n)                                                       \
        XN[s][n] = *(const u16x4*)(xlane + ((size_t)(tl * 2 + s)) * 24576 + n * 8192);  \
    GRU_STEP(tp_ * 2, XC[0]);                                                           \
    GRU_STEP(tp_ * 2 + 1, XC[1]);                                                       \
  }

#pragma unroll 1
  for (int tp = 0; tp < 64; tp += 2) {
    GRU_PAIR(tp, xA, xB);
    GRU_PAIR(tp + 1, xB, xA);
  }
#undef GRU_PAIR
#undef GRU_STEP
}

// ---------------- pooling + MLP heads + signal equation ----------------
__global__ __launch_bounds__(256) void k_heads(
    const unsigned short* __restrict__ gout,
    const float* __restrict__ swT, const float* __restrict__ swM,
    const float* __restrict__ tw1, const float* __restrict__ tb1,
    const float* __restrict__ tw2, const float* __restrict__ tb2,
    const float* __restrict__ tw3, const float* __restrict__ tb3,
    const float* __restrict__ mw1, const float* __restrict__ mb1,
    const float* __restrict__ mw2, const float* __restrict__ mb2,
    const float* __restrict__ mw3, const float* __restrict__ mb3,
    const float* __restrict__ fav, const float* __restrict__ TRv,
    float* __restrict__ out) {
  __shared__ float hbuf[128 * 129];
  __shared__ float pp[2][128][2];
  __shared__ float pT[128], pM[128];
  __shared__ float hidT[128], hidM[128];
  __shared__ float l1b[200], l2b[200];
  __shared__ float parts[4];
  __shared__ float scal[2];
  const int tid = threadIdx.x;
  const int b = blockIdx.x;
#pragma unroll
  for (int rep = 0; rep < 8; ++rep) {
    int idx = rep * 2048 + tid * 8;
    int row = idx >> 7, col = idx & 127;
    bf16x8 v = *(const bf16x8*)(gout + (size_t)b * (LQ * NH) + idx);
#pragma unroll
    for (int j = 0; j < 8; ++j)
      hbuf[row * 129 + col + j] = b2f((unsigned short)v[j]);
  }
  __syncthreads();
  {
    int t = tid & 127, hf2 = tid >> 7;
    float aT = 0.f, aM = 0.f;
    for (int j = 0; j < 64; ++j) {
      float v = hbuf[t * 129 + hf2 * 64 + j];
      aT = fmaf(v, swT[hf2 * 64 + j], aT);
      aM = fmaf(v, swM[hf2 * 64 + j], aM);
    }
    pp[hf2][t][0] = aT;
    pp[hf2][t][1] = aM;
  }
  __syncthreads();
  if (tid < 64) {
    float v0 = pp[0][tid][0] + pp[1][tid][0];
    float v1 = pp[0][tid + 64][0] + pp[1][tid + 64][0];
    float m = fmaxf(v0, v1);
    for (int off = 32; off > 0; off >>= 1) m = fmaxf(m, __shfl_xor(m, off));
    float p0 = __expf(v0 - m), p1 = __expf(v1 - m);
    float s = p0 + p1;
    for (int off = 32; off > 0; off >>= 1) s += __shfl_xor(s, off);
    float inv = 1.f / s;
    pT[tid] = p0 * inv; pT[tid + 64] = p1 * inv;
  } else if (tid < 128) {
    int l = tid - 64;
    float v0 = pp[0][l][1] + pp[1][l][1];
    float v1 = pp[0][l + 64][1] + pp[1][l + 64][1];
    float m = fmaxf(v0, v1);
    for (int off = 32; off > 0; off >>= 1) m = fmaxf(m, __shfl_xor(m, off));
    float p0 = __expf(v0 - m), p1 = __expf(v1 - m);
    float s = p0 + p1;
    for (int off = 32; off > 0; off >>= 1) s += __shfl_xor(s, off);
    float inv = 1.f / s;
    pM[l] = p0 * inv; pM[l + 64] = p1 * inv;
  }
  __syncthreads();
  {
    int j = tid & 127, hf2 = tid >> 7;
    float aT = 0.f, aM = 0.f;
    for (int t2 = 0; t2 < 64; ++t2) {
      int t = hf2 * 64 + t2;
      float v = hbuf[t * 129 + j];
      aT = fmaf(v, pT[t], aT);
      aM = fmaf(v, pM[t], aM);
    }
    pp[hf2][j][0] = aT;
    pp[hf2][j][1] = aM;
  }
  __syncthreads();
  if (tid < 128) {
    hidT[tid] = pp[0][tid][0] + pp[1][tid][0];
    hidM[tid] = pp[0][tid][1] + pp[1][tid][1];
  }
  __syncthreads();
#pragma unroll 1
  for (int hd = 0; hd < 2; ++hd) {
    const float* in = hd ? hidM : hidT;
    const float* w1 = hd ? mw1 : tw1; const float* b1 = hd ? mb1 : tb1;
    const float* w2 = hd ? mw2 : tw2; const float* b2 = hd ? mb2 : tb2;
    const float* w3 = hd ? mw3 : tw3; const float* b3 = hd ? mb3 : tb3;
    if (tid < 200) {
      float acc = b1[tid];
      for (int j4 = 0; j4 < 32; ++j4) {
        float4 wv = *(const float4*)(w1 + tid * 128 + j4 * 4);
        acc += wv.x * in[j4 * 4] + wv.y * in[j4 * 4 + 1] + wv.z * in[j4 * 4 + 2] + wv.w * in[j4 * 4 + 3];
      }
      l1b[tid] = gelu_f(acc);
    }
    __syncthreads();
    if (tid < 200) {
      float acc = b2[tid];
      for (int k4 = 0; k4 < 50; ++k4) {
        float4 wv = *(const float4*)(w2 + tid * 200 + k4 * 4);
        acc += wv.x * l1b[k4 * 4] + wv.y * l1b[k4 * 4 + 1] + wv.z * l1b[k4 * 4 + 2] + wv.w * l1b[k4 * 4 + 3];
      }
      l2b[tid] = gelu_f(acc);
    }
    __syncthreads();
    float part = (tid < 200) ? l2b[tid] * w3[tid] : 0.f;
    for (int off = 32; off > 0; off >>= 1) part += __shfl_xor(part, off);
    if ((tid & 63) == 0) parts[tid >> 6] = part;
    __syncthreads();
    if (tid == 0) {
      float y = parts[0] + parts[1] + parts[2] + parts[3] + b3[0];
      float hi = hd ? 10.f : 5.f;
      float val = 0.1f + sigm(y) * (hi - 0.1f);
      scal[hd] = val;
      out[BS * SEQ + hd * BS + b] = val;
    }
    __syncthreads();
  }
  float T10 = scal[0], M0 = scal[1];
  float R1 = 1.f / T10;
  for (int i = tid; i < SEQ; i += 256) {
    float fa = fav[b * SEQ + i];
    float tr = TRv[b * SEQ + i];
    float E = __expf(-tr * R1);
    float s, c;
    __sincosf(fa, &s, &c);
    out[b * SEQ + i] = (1.f - E) * s / (1.f - c * E) * M0;
  }
}

// ---------------- launch ----------------
extern "C" void kernel_launch(void* const* d_in, const int* in_sizes, int n_in,
                              void* d_out, int out_size, void* d_ws, size_t ws_size,
                              hipStream_t stream) {
  const float* Xfa = (const float*)d_in[0];
  const float* fav = (const float*)d_in[1];
  const void*  mraw = d_in[2];
  const float* TRv = (const float*)d_in[4];
  const float* lw = (const float*)d_in[5];
  const float* lb = (const float*)d_in[6];
  const float* pw = (const float*)d_in[7];
  const float* pb = (const float*)d_in[8];
  const float* qw = (const float*)d_in[9];
  const float* qb = (const float*)d_in[10];
  const float* kw = (const float*)d_in[11];
  const float* kb = (const float*)d_in[12];
  const float* aow = (const float*)d_in[13];
  const float* aob = (const float*)d_in[14];
  const float* wih = (const float*)d_in[15];
  const float* whh = (const float*)d_in[16];
  const float* bih = (const float*)d_in[17];
  const float* bhh = (const float*)d_in[18];
  const float* swT = (const float*)d_in[19];
  const float* swM = (const float*)d_in[20];
  const float* tw1 = (const float*)d_in[21];
  const float* tb1 = (const float*)d_in[22];
  const float* tw2 = (const float*)d_in[23];
  const float* tb2 = (const float*)d_in[24];
  const float* tw3 = (const float*)d_in[25];
  const float* tb3 = (const float*)d_in[26];
  const float* mw1 = (const float*)d_in[27];
  const float* mb1 = (const float*)d_in[28];
  const float* mw2 = (const float*)d_in[29];
  const float* mb2 = (const float*)d_in[30];
  const float* mw3 = (const float*)d_in[31];
  const float* mb3 = (const float*)d_in[32];
  float* out = (float*)d_out;
  char* ws = (char*)d_ws;

  unsigned short* qbf = (unsigned short*)ws;              // 0       .. 32768
  float* part = (float*)(ws + 32768);                     // 2 MB (aliases gout; dead before gru writes)
  unsigned short* gout = (unsigned short*)(ws + 32768);   // 2 MB    .. 2129920
  float* fwc = (float*)(ws + 2129920);                    //         .. 2148352
  unsigned short* xgate = (unsigned short*)(ws + 2148352);// 6.29 MB .. 8439808

  k_prep<<<9, 384, 0, stream>>>(qw, qb, lw, lb, pw, pb,
                                wih, bih, bhh, aow, aob, qbf, fwc);
  k_attn<<<256, 256, 0, stream>>>(Xfa, mraw, fav, kw, kb, lw, lb, pw, pb, qbf, part);
  k_xgate<<<128, 384, 0, stream>>>(fwc, part, xgate);
  k_gru11<<<4, 512, 0, stream>>>(whh, bhh, xgate, gout);
  k_heads<<<64, 256, 0, stream>>>(gout, swT, swM, tw1, tb1, tw2, tb2, tw3, tb3,
                                  mw1, mb1, mw2, mb2, mw3, mb3, fav, TRv, out);
}